// Round 10
// baseline (115.593 us; speedup 1.0000x reference)
//
#include <hip/hip_runtime.h>
#include <hip/hip_bf16.h>
#include <math.h>

#define N_NODES 8192
#define IN_DIM  512
#define OUT_DIM 512
#define KN      16
#define CAP     128
#define QPB     16

typedef __attribute__((ext_vector_type(8))) short bf16x8;
typedef __attribute__((ext_vector_type(4))) float f32x4;
typedef __attribute__((ext_vector_type(2))) float v2f;
typedef __attribute__((ext_vector_type(2))) _Float16 h2;

__device__ __forceinline__ ushort f2bf(float x) {
  __hip_bfloat16 b = __float2bfloat16(x);
  return *reinterpret_cast<ushort*>(&b);
}
__device__ __forceinline__ ushort f2h(float x) {
  _Float16 v = (_Float16)x;
  return __builtin_bit_cast(unsigned short, v);
}
__device__ __forceinline__ v2f fma2(v2f a, v2f b, v2f c) { return __builtin_elementwise_fma(a, b, c); }
__device__ __forceinline__ v2f max2(v2f a, v2f b) { return __builtin_elementwise_max(a, b); }
__device__ __forceinline__ v2f splat2(float x) { v2f r; r.x = x; r.y = x; return r; }

__device__ __forceinline__ float dot2acc(unsigned qu, unsigned ku, float acc) {
#if __has_builtin(__builtin_amdgcn_fdot2)
  return __builtin_amdgcn_fdot2(__builtin_bit_cast(h2, qu), __builtin_bit_cast(h2, ku), acc, false);
#else
  h2 q = __builtin_bit_cast(h2, qu), k = __builtin_bit_cast(h2, ku);
  acc = fmaf((float)q.x, (float)k.x, acc);
  return fmaf((float)q.y, (float)k.y, acc);
#endif
}

#define GLOAD_LDS16(gp, lp)                                                     \
  __builtin_amdgcn_global_load_lds((const __attribute__((address_space(1))) void*)(gp), \
                                   (__attribute__((address_space(3))) void*)(lp), 16, 0, 0)

// ------- fused prep: blocks <2048 do h->A2(bf16 hi) + f64 G; rest split W ----
__global__ __launch_bounds__(256) void prep_split(
    const float* __restrict__ h, const float* __restrict__ Wg,
    const float* __restrict__ Wq, const float* __restrict__ Wk,
    const float* __restrict__ Wv,
    ushort* __restrict__ A2, ushort* __restrict__ B,
    double* __restrict__ Gx, double* __restrict__ Gy,
    double* __restrict__ Gz, double* __restrict__ Gsq,
    float4* __restrict__ gpk) {
  if (blockIdx.x < 2048) {
    const int node = (blockIdx.x * 256 + threadIdx.x) >> 6;
    const int lane = threadIdx.x & 63;
    const int k = lane * 8;
    const float* hr = h + (size_t)node * IN_DIM;

    float4 v0 = *(const float4*)&hr[k];
    float4 v1 = *(const float4*)&hr[k + 4];

    ushort4 hiA = make_ushort4(f2bf(v0.x), f2bf(v0.y), f2bf(v0.z), f2bf(v0.w));
    ushort4 hiB = make_ushort4(f2bf(v1.x), f2bf(v1.y), f2bf(v1.z), f2bf(v1.w));
    size_t base = (size_t)node * 512 + k;
    *(ushort4*)&A2[base]     = hiA;
    *(ushort4*)&A2[base + 4] = hiB;

    float4 w0a = *(const float4*)&Wg[0 * IN_DIM + k];
    float4 w0b = *(const float4*)&Wg[0 * IN_DIM + k + 4];
    float4 w1a = *(const float4*)&Wg[1 * IN_DIM + k];
    float4 w1b = *(const float4*)&Wg[1 * IN_DIM + k + 4];
    float4 w2a = *(const float4*)&Wg[2 * IN_DIM + k];
    float4 w2b = *(const float4*)&Wg[2 * IN_DIM + k + 4];

    double s0 = 0.0, s1 = 0.0, s2 = 0.0;
    s0 += (double)v0.x * w0a.x; s0 += (double)v0.y * w0a.y;
    s0 += (double)v0.z * w0a.z; s0 += (double)v0.w * w0a.w;
    s0 += (double)v1.x * w0b.x; s0 += (double)v1.y * w0b.y;
    s0 += (double)v1.z * w0b.z; s0 += (double)v1.w * w0b.w;
    s1 += (double)v0.x * w1a.x; s1 += (double)v0.y * w1a.y;
    s1 += (double)v0.z * w1a.z; s1 += (double)v0.w * w1a.w;
    s1 += (double)v1.x * w1b.x; s1 += (double)v1.y * w1b.y;
    s1 += (double)v1.z * w1b.z; s1 += (double)v1.w * w1b.w;
    s2 += (double)v0.x * w2a.x; s2 += (double)v0.y * w2a.y;
    s2 += (double)v0.z * w2a.z; s2 += (double)v0.w * w2a.w;
    s2 += (double)v1.x * w2b.x; s2 += (double)v1.y * w2b.y;
    s2 += (double)v1.z * w2b.z; s2 += (double)v1.w * w2b.w;

    #pragma unroll
    for (int off = 32; off; off >>= 1) {
      s0 += __shfl_down(s0, off);
      s1 += __shfl_down(s1, off);
      s2 += __shfl_down(s2, off);
    }
    if (lane == 0) {
      double sq = s0 * s0 + s1 * s1 + s2 * s2;
      Gx[node] = s0; Gy[node] = s1; Gz[node] = s2; Gsq[node] = sq;
      gpk[node] = make_float4((float)s0, (float)s1, (float)s2, -(float)sq);
    }
  } else {
    int i = (blockIdx.x - 2048) * 256 + threadIdx.x;
    int n  = i >> 7;
    int kc = (i & 127) << 2;
    const float* W = (n < 512) ? Wq : (n < 1024) ? Wk : Wv;
    int r = n & 511;
    float4 v = *(const float4*)&W[(size_t)r * 512 + kc];
    *(ushort4*)&B[(size_t)n * 512 + kc] =
        make_ushort4(f2bf(v.x), f2bf(v.y), f2bf(v.z), f2bf(v.w));
  }
}

// ---------------- Q/K/V bf16 MFMA GEMM, uniform K=512, f16 output --------
__global__ __launch_bounds__(256) void gemm_qkv(
    const ushort* __restrict__ A2, const ushort* __restrict__ B,
    ushort* __restrict__ Q2, ushort* __restrict__ K2, ushort* __restrict__ V2) {
  __shared__ ushort lA[128 * 32];
  __shared__ ushort lB[128 * 32];
  const int tid = threadIdx.x, w = tid >> 6, lane = tid & 63;
  const int id = blockIdx.x;
  const int sw = (id & 7) * 96 + (id >> 3);   // XCD-contiguous (768%8==0)
  const int bm = sw / 12, bn = sw % 12;
  const int wr = w >> 1, wc = w & 1;

  f32x4 acc[4][4] = {};

  const int   srow = w * 32 + (lane >> 2);
  const int   scol = (lane & 3) * 8;
  const size_t gA0 = (size_t)(bm * 128 + srow) * 512 + scol;
  const size_t gB0 = (size_t)(bn * 128 + srow) * 512 + scol;

  for (int k0 = 0; k0 < 512; k0 += 32) {
    GLOAD_LDS16(&A2[gA0 + k0],            &lA[w * 1024]);
    GLOAD_LDS16(&A2[gA0 + 16 * 512 + k0], &lA[w * 1024 + 512]);
    GLOAD_LDS16(&B[gB0 + k0],             &lB[w * 1024]);
    GLOAD_LDS16(&B[gB0 + 16 * 512 + k0],  &lB[w * 1024 + 512]);
    __syncthreads();

    const int ar = wr * 64 + (lane & 15);
    const int br = wc * 64 + (lane & 15);
    const int kc = (lane >> 4) * 8;
    bf16x8 af[4], bfr[4];
    #pragma unroll
    for (int f = 0; f < 4; ++f) {
      af[f]  = *(const bf16x8*)&lA[(ar + f * 16) * 32 + kc];
      bfr[f] = *(const bf16x8*)&lB[(br + f * 16) * 32 + kc];
    }
    #pragma unroll
    for (int fm = 0; fm < 4; ++fm)
      #pragma unroll
      for (int fn = 0; fn < 4; ++fn)
        acc[fm][fn] = __builtin_amdgcn_mfma_f32_16x16x32_bf16(af[fm], bfr[fn], acc[fm][fn], 0, 0, 0);
    __syncthreads();
  }

  ushort* Cm = (bn < 4) ? Q2 : (bn < 8) ? K2 : V2;
  const int col  = (bn & 3) * 128 + wc * 64 + (lane & 15);
  const int row0 = bm * 128 + wr * 64 + (lane >> 4) * 4;
  #pragma unroll
  for (int fm = 0; fm < 4; ++fm)
    #pragma unroll
    for (int fn = 0; fn < 4; ++fn)
      #pragma unroll
      for (int r = 0; r < 4; ++r)
        Cm[(size_t)(row0 + fm * 16 + r) * 512 + col + fn * 16] = f2h(acc[fm][fn][r]);
}

// ---------------- knn: 16 queries/block, packed-f32 scan, radix-select ---
// LDS overlay: s_tmax (phases A/B) shares storage with s_dval (phase D).
__global__ __launch_bounds__(256) void knn_kernel(
    const float4* __restrict__ gpk,
    const double* __restrict__ Gx, const double* __restrict__ Gy,
    const double* __restrict__ Gz, const double* __restrict__ Gsq,
    int* __restrict__ knn) {
  const int tid   = threadIdx.x;
  const int w     = tid >> 6;
  const int lane  = tid & 63;
  const int qbase = blockIdx.x * QPB;

  __shared__ unsigned long long ovl[QPB * 256 / 2];   // 16 KB: tmax | dval
  __shared__ int   s_cand[QPB][CAP];                  // 8 KB
  __shared__ int   s_cnt[QPB];
  __shared__ float s_T[QPB];
  float (*s_tmax)[256] = (float(*)[256])ovl;
  double(*s_dval)[CAP] = (double(*)[CAP])ovl;

  float q2x[QPB], q2y[QPB], q2z[QPB];
  v2f tm2[QPB];
  #pragma unroll
  for (int s = 0; s < QPB; ++s) {
    float4 qv = gpk[qbase + s];
    q2x[s] = 2.f * qv.x; q2y[s] = 2.f * qv.y; q2z[s] = 2.f * qv.z;
    tm2[s] = splat2(-1e30f);
  }
  if (tid < QPB) s_cnt[tid] = 0;

  // Phase A: packed branchless max scan with register prefetch
  {
    float4 c0 = gpk[tid];
    float4 c1 = gpk[tid + 256];
    for (int i = 0; i < 16; ++i) {
      int nx = ((i + 1) & 15) * 512;
      float4 n0 = gpk[tid + nx];
      float4 n1 = gpk[tid + nx + 256];
      v2f cx, cy, cz, cw;
      cx.x = c0.x; cx.y = c1.x;
      cy.x = c0.y; cy.y = c1.y;
      cz.x = c0.z; cz.y = c1.z;
      cw.x = c0.w; cw.y = c1.w;
      #pragma unroll
      for (int s = 0; s < QPB; ++s) {
        v2f v = fma2(splat2(q2x[s]), cx,
                 fma2(splat2(q2y[s]), cy,
                  fma2(splat2(q2z[s]), cz, cw)));
        tm2[s] = max2(tm2[s], v);
      }
      c0 = n0; c1 = n1;
    }
  }
  #pragma unroll
  for (int s = 0; s < QPB; ++s) s_tmax[s][tid] = fmaxf(tm2[s].x, tm2[s].y);
  __syncthreads();

  // Phase B: wave w handles queries w*4..w*4+3; exact 16th-of-64 radix select
  #pragma unroll
  for (int qq = 0; qq < 4; ++qq) {
    int q = w * 4 + qq;
    float v = fmaxf(fmaxf(s_tmax[q][lane], s_tmax[q][lane + 64]),
                    fmaxf(s_tmax[q][lane + 128], s_tmax[q][lane + 192]));
    unsigned b = __float_as_uint(v);
    unsigned u = b ^ ((unsigned)((int)b >> 31) | 0x80000000u);
    unsigned thr = 0;
    for (int bit = 31; bit >= 0; --bit) {
      unsigned cand = thr | (1u << bit);
      unsigned long long m = __ballot(u >= cand);
      if (__popcll(m) >= KN) thr = cand;
    }
    unsigned tb = (thr & 0x80000000u) ? (thr ^ 0x80000000u) : ~thr;
    if (lane == 0) s_T[q] = __uint_as_float(tb);
  }
  __syncthreads();

  // Phase C: packed rescan (identical FMA chain), collect candidates >= T
  float Ts[QPB];
  #pragma unroll
  for (int s = 0; s < QPB; ++s) Ts[s] = s_T[s];
  {
    float4 c0 = gpk[tid];
    float4 c1 = gpk[tid + 256];
    for (int i = 0; i < 16; ++i) {
      int nx = ((i + 1) & 15) * 512;
      float4 n0 = gpk[tid + nx];
      float4 n1 = gpk[tid + nx + 256];
      int j0 = tid + i * 512, j1 = j0 + 256;
      v2f cx, cy, cz, cw;
      cx.x = c0.x; cx.y = c1.x;
      cy.x = c0.y; cy.y = c1.y;
      cz.x = c0.z; cz.y = c1.z;
      cw.x = c0.w; cw.y = c1.w;
      #pragma unroll
      for (int s = 0; s < QPB; ++s) {
        v2f v = fma2(splat2(q2x[s]), cx,
                 fma2(splat2(q2y[s]), cy,
                  fma2(splat2(q2z[s]), cz, cw)));
        if (v.x >= Ts[s]) { int p = atomicAdd(&s_cnt[s], 1); if (p < CAP) s_cand[s][p] = j0; }
        if (v.y >= Ts[s]) { int p = atomicAdd(&s_cnt[s], 1); if (p < CAP) s_cand[s][p] = j1; }
      }
      c0 = n0; c1 = n1;
    }
  }
  __syncthreads();

  // Phase D: exact f64 scores for wave's 4 queries (write), then rank (count)
  int   jj0[4], jj1[4];
  double vv0[4], vv1[4];
  int   cnts[4];
  #pragma unroll
  for (int qq = 0; qq < 4; ++qq) {
    int q  = w * 4 + qq;
    int gq = qbase + q;
    int cnt = min(s_cnt[q], CAP);
    cnts[qq] = cnt;
    double xi = Gx[gq], yi = Gy[gq], zi = Gz[gq], sqi = Gsq[gq];
    jj0[qq] = -1; jj1[qq] = -1; vv0[qq] = 0; vv1[qq] = 0;
    if (lane < cnt) {
      int j = s_cand[q][lane];
      vv0[qq] = 2.0 * (xi * Gx[j] + yi * Gy[j] + zi * Gz[j]) - sqi - Gsq[j];
      jj0[qq] = j;
      s_dval[q][lane] = vv0[qq];
    }
    if (lane + 64 < cnt) {
      int j = s_cand[q][lane + 64];
      vv1[qq] = 2.0 * (xi * Gx[j] + yi * Gy[j] + zi * Gz[j]) - sqi - Gsq[j];
      jj1[qq] = j;
      s_dval[q][lane + 64] = vv1[qq];
    }
  }
  __syncthreads();
  #pragma unroll
  for (int qq = 0; qq < 4; ++qq) {
    int q  = w * 4 + qq;
    int gq = qbase + q;
    int cnt = cnts[qq];
    int r0 = 0, r1 = 0;
    for (int m = 0; m < cnt; ++m) {
      double dv = s_dval[q][m]; int di = s_cand[q][m];
      r0 += (dv > vv0[qq]) || (dv == vv0[qq] && di < jj0[qq]);
      r1 += (dv > vv1[qq]) || (dv == vv1[qq] && di < jj1[qq]);
    }
    if (jj0[qq] >= 0 && r0 < KN) knn[gq * KN + r0] = jj0[qq];
    if (jj1[qq] >= 0 && r1 < KN) knn[gq * KN + r1] = jj1[qq];
  }
}

// ---------------- attend: per dst node, 16 neighbors, f16 Q/K/V ----------
__global__ __launch_bounds__(256) void attend_kernel(
    const ushort* __restrict__ Q2, const ushort* __restrict__ K2, const ushort* __restrict__ V2,
    const float4* __restrict__ gpk,
    const int* __restrict__ knn, float* __restrict__ out) {
  const int i    = blockIdx.x;
  const int tid  = threadIdx.x;
  const int wv   = tid >> 6;
  const int lane = tid & 63;

  __shared__ int   s_idx[KN];
  __shared__ float s_sc[KN];
  __shared__ float s_w[KN];
  __shared__ float s_se[KN];

  if (tid < KN) s_idx[tid] = knn[i * KN + tid];
  __syncthreads();

  uint4 qa = *(const uint4*)&Q2[(size_t)i * 512 + lane * 8];

  float partial[4];
  #pragma unroll
  for (int s = 0; s < 4; ++s) {
    int src = s_idx[wv * 4 + s];
    uint4 ka = *(const uint4*)&K2[(size_t)src * 512 + lane * 8];
    float acc = dot2acc(qa.x, ka.x, 0.f);
    acc = dot2acc(qa.y, ka.y, acc);
    acc = dot2acc(qa.z, ka.z, acc);
    acc = dot2acc(qa.w, ka.w, acc);
    partial[s] = acc;
  }
  #pragma unroll
  for (int s = 0; s < 4; ++s)
    #pragma unroll
    for (int off = 32; off; off >>= 1) partial[s] += __shfl_down(partial[s], off);

  if (lane == 0) {
    #pragma unroll
    for (int s = 0; s < 4; ++s) s_sc[wv * 4 + s] = partial[s];
  }
  __syncthreads();

  // 16 threads compute the 16 edge weights in parallel (2 expf each)
  if (tid < KN) {
    int e = tid;
    int src = s_idx[e];
    float4 gi = gpk[i];
    float4 gs = gpk[src];
    float sc = s_sc[e] * (1.f / 22.627417f);
    sc = fminf(fmaxf(sc, -5.f), 5.f);
    float se = expf(sc);
    float dx = gi.x - gs.x, dy = gi.y - gs.y, dz = gi.z - gs.z;
    float dd = -sqrtf(fmaf(dx, dx, fmaf(dy, dy, fmaf(dz, dz, 1e-6f))));
    float dc = fminf(fmaxf(dd * (1.f / 22.627417f), -5.f), 5.f);
    float de = expf(dc);
    s_se[e] = se;
    s_w[e]  = se * de;
  }
  __syncthreads();

  float z = 0.f;
  #pragma unroll
  for (int e = 0; e < KN; ++e) z += s_se[e];

  const int d = tid * 2;
  float a0 = 0.f, a1 = 0.f;
  #pragma unroll
  for (int e = 0; e < KN; ++e) {
    unsigned vv = *(const unsigned*)&V2[(size_t)s_idx[e] * 512 + d];
    h2 vh = __builtin_bit_cast(h2, vv);
    a0 = fmaf(s_w[e], (float)vh.x, a0);
    a1 = fmaf(s_w[e], (float)vh.y, a1);
  }
  float inv = (z > 0.f) ? (1.f / z) : 1.f;
  float2 o = make_float2(a0 * inv, a1 * inv);
  *(float2*)&out[(size_t)i * 512 + d] = o;
}

extern "C" void kernel_launch(void* const* d_in, const int* in_sizes, int n_in,
                              void* d_out, int out_size, void* d_ws, size_t ws_size,
                              hipStream_t stream) {
  const float* h  = (const float*)d_in[0];
  const float* Wq = (const float*)d_in[1];
  const float* Wk = (const float*)d_in[2];
  const float* Wv = (const float*)d_in[3];
  const float* Wg = (const float*)d_in[4];
  float* out = (float*)d_out;

  char* ws = (char*)d_ws;
  ushort* A2  = (ushort*)(ws);                 // 8 MB
  ushort* B   = (ushort*)(ws + (8u << 20));    // 1.5 MB
  ushort* Q2  = (ushort*)(ws + (10u << 20));   // 8 MB (f16)
  ushort* K2  = (ushort*)(ws + (18u << 20));   // 8 MB (f16)
  ushort* V2  = (ushort*)(ws + (26u << 20));   // 8 MB (f16)
  float4* gpk = (float4*)(ws + (34u << 20));   // 128 KB
  double* Gx  = (double*)(ws + (34u << 20) + (1u << 17));
  double* Gy  = Gx + N_NODES;
  double* Gz  = Gy + N_NODES;
  double* Gsq = Gz + N_NODES;
  int*    knn = (int*)(Gsq + N_NODES);         // 512 KB

  hipLaunchKernelGGL(prep_split, dim3(2048 + 768), dim3(256), 0, stream,
                     h, Wg, Wq, Wk, Wv, A2, B, Gx, Gy, Gz, Gsq, gpk);
  hipLaunchKernelGGL(gemm_qkv, dim3(768), dim3(256), 0, stream,
                     A2, B, Q2, K2, V2);
  hipLaunchKernelGGL(knn_kernel, dim3(N_NODES / QPB), dim3(256), 0, stream,
                     gpk, Gx, Gy, Gz, Gsq, knn);
  hipLaunchKernelGGL(attend_kernel, dim3(N_NODES), dim3(256), 0, stream,
                     Q2, K2, V2, gpk, knn, out);
}

// Round 11
// 93.536 us; speedup vs baseline: 1.2358x; 1.2358x over previous
//
#include <hip/hip_runtime.h>
#include <hip/hip_bf16.h>
#include <math.h>

#define N_NODES 8192
#define IN_DIM  512
#define OUT_DIM 512
#define KN      16
#define CAP     128
#define QPB     8

typedef __attribute__((ext_vector_type(8))) short bf16x8;
typedef __attribute__((ext_vector_type(4))) float f32x4;
typedef __attribute__((ext_vector_type(2))) float v2f;
typedef __attribute__((ext_vector_type(2))) _Float16 h2;

__device__ __forceinline__ ushort f2bf(float x) {
  __hip_bfloat16 b = __float2bfloat16(x);
  return *reinterpret_cast<ushort*>(&b);
}
__device__ __forceinline__ ushort f2h(float x) {
  _Float16 v = (_Float16)x;
  return __builtin_bit_cast(unsigned short, v);
}
__device__ __forceinline__ v2f fma2(v2f a, v2f b, v2f c) { return __builtin_elementwise_fma(a, b, c); }
__device__ __forceinline__ v2f max2(v2f a, v2f b) { return __builtin_elementwise_max(a, b); }
__device__ __forceinline__ v2f splat2(float x) { v2f r; r.x = x; r.y = x; return r; }

__device__ __forceinline__ float dot2acc(unsigned qu, unsigned ku, float acc) {
#if __has_builtin(__builtin_amdgcn_fdot2)
  return __builtin_amdgcn_fdot2(__builtin_bit_cast(h2, qu), __builtin_bit_cast(h2, ku), acc, false);
#else
  h2 q = __builtin_bit_cast(h2, qu), k = __builtin_bit_cast(h2, ku);
  acc = fmaf((float)q.x, (float)k.x, acc);
  return fmaf((float)q.y, (float)k.y, acc);
#endif
}

#define GLOAD_LDS16(gp, lp)                                                     \
  __builtin_amdgcn_global_load_lds((const __attribute__((address_space(1))) void*)(gp), \
                                   (__attribute__((address_space(3))) void*)(lp), 16, 0, 0)

// ------- fused prep: blocks <2048 do h->A2(bf16 hi) + f64 G; rest split W ----
__global__ __launch_bounds__(256) void prep_split(
    const float* __restrict__ h, const float* __restrict__ Wg,
    const float* __restrict__ Wq, const float* __restrict__ Wk,
    const float* __restrict__ Wv,
    ushort* __restrict__ A2, ushort* __restrict__ B,
    double* __restrict__ Gx, double* __restrict__ Gy,
    double* __restrict__ Gz, double* __restrict__ Gsq,
    float4* __restrict__ gpk) {
  if (blockIdx.x < 2048) {
    const int node = (blockIdx.x * 256 + threadIdx.x) >> 6;
    const int lane = threadIdx.x & 63;
    const int k = lane * 8;
    const float* hr = h + (size_t)node * IN_DIM;

    float4 v0 = *(const float4*)&hr[k];
    float4 v1 = *(const float4*)&hr[k + 4];

    ushort4 hiA = make_ushort4(f2bf(v0.x), f2bf(v0.y), f2bf(v0.z), f2bf(v0.w));
    ushort4 hiB = make_ushort4(f2bf(v1.x), f2bf(v1.y), f2bf(v1.z), f2bf(v1.w));
    size_t base = (size_t)node * 512 + k;
    *(ushort4*)&A2[base]     = hiA;
    *(ushort4*)&A2[base + 4] = hiB;

    float4 w0a = *(const float4*)&Wg[0 * IN_DIM + k];
    float4 w0b = *(const float4*)&Wg[0 * IN_DIM + k + 4];
    float4 w1a = *(const float4*)&Wg[1 * IN_DIM + k];
    float4 w1b = *(const float4*)&Wg[1 * IN_DIM + k + 4];
    float4 w2a = *(const float4*)&Wg[2 * IN_DIM + k];
    float4 w2b = *(const float4*)&Wg[2 * IN_DIM + k + 4];

    double s0 = 0.0, s1 = 0.0, s2 = 0.0;
    s0 += (double)v0.x * w0a.x; s0 += (double)v0.y * w0a.y;
    s0 += (double)v0.z * w0a.z; s0 += (double)v0.w * w0a.w;
    s0 += (double)v1.x * w0b.x; s0 += (double)v1.y * w0b.y;
    s0 += (double)v1.z * w0b.z; s0 += (double)v1.w * w0b.w;
    s1 += (double)v0.x * w1a.x; s1 += (double)v0.y * w1a.y;
    s1 += (double)v0.z * w1a.z; s1 += (double)v0.w * w1a.w;
    s1 += (double)v1.x * w1b.x; s1 += (double)v1.y * w1b.y;
    s1 += (double)v1.z * w1b.z; s1 += (double)v1.w * w1b.w;
    s2 += (double)v0.x * w2a.x; s2 += (double)v0.y * w2a.y;
    s2 += (double)v0.z * w2a.z; s2 += (double)v0.w * w2a.w;
    s2 += (double)v1.x * w2b.x; s2 += (double)v1.y * w2b.y;
    s2 += (double)v1.z * w2b.z; s2 += (double)v1.w * w2b.w;

    #pragma unroll
    for (int off = 32; off; off >>= 1) {
      s0 += __shfl_down(s0, off);
      s1 += __shfl_down(s1, off);
      s2 += __shfl_down(s2, off);
    }
    if (lane == 0) {
      double sq = s0 * s0 + s1 * s1 + s2 * s2;
      Gx[node] = s0; Gy[node] = s1; Gz[node] = s2; Gsq[node] = sq;
      gpk[node] = make_float4((float)s0, (float)s1, (float)s2, -(float)sq);
    }
  } else {
    int i = (blockIdx.x - 2048) * 256 + threadIdx.x;
    int n  = i >> 7;
    int kc = (i & 127) << 2;
    const float* W = (n < 512) ? Wq : (n < 1024) ? Wk : Wv;
    int r = n & 511;
    float4 v = *(const float4*)&W[(size_t)r * 512 + kc];
    *(ushort4*)&B[(size_t)n * 512 + kc] =
        make_ushort4(f2bf(v.x), f2bf(v.y), f2bf(v.z), f2bf(v.w));
  }
}

// ---------------- Q/K/V bf16 MFMA GEMM, uniform K=512, f16 output --------
__global__ __launch_bounds__(256) void gemm_qkv(
    const ushort* __restrict__ A2, const ushort* __restrict__ B,
    ushort* __restrict__ Q2, ushort* __restrict__ K2, ushort* __restrict__ V2) {
  __shared__ ushort lA[128 * 32];
  __shared__ ushort lB[128 * 32];
  const int tid = threadIdx.x, w = tid >> 6, lane = tid & 63;
  const int id = blockIdx.x;
  const int sw = (id & 7) * 96 + (id >> 3);   // XCD-contiguous (768%8==0)
  const int bm = sw / 12, bn = sw % 12;
  const int wr = w >> 1, wc = w & 1;

  f32x4 acc[4][4] = {};

  const int   srow = w * 32 + (lane >> 2);
  const int   scol = (lane & 3) * 8;
  const size_t gA0 = (size_t)(bm * 128 + srow) * 512 + scol;
  const size_t gB0 = (size_t)(bn * 128 + srow) * 512 + scol;

  for (int k0 = 0; k0 < 512; k0 += 32) {
    GLOAD_LDS16(&A2[gA0 + k0],            &lA[w * 1024]);
    GLOAD_LDS16(&A2[gA0 + 16 * 512 + k0], &lA[w * 1024 + 512]);
    GLOAD_LDS16(&B[gB0 + k0],             &lB[w * 1024]);
    GLOAD_LDS16(&B[gB0 + 16 * 512 + k0],  &lB[w * 1024 + 512]);
    __syncthreads();

    const int ar = wr * 64 + (lane & 15);
    const int br = wc * 64 + (lane & 15);
    const int kc = (lane >> 4) * 8;
    bf16x8 af[4], bfr[4];
    #pragma unroll
    for (int f = 0; f < 4; ++f) {
      af[f]  = *(const bf16x8*)&lA[(ar + f * 16) * 32 + kc];
      bfr[f] = *(const bf16x8*)&lB[(br + f * 16) * 32 + kc];
    }
    #pragma unroll
    for (int fm = 0; fm < 4; ++fm)
      #pragma unroll
      for (int fn = 0; fn < 4; ++fn)
        acc[fm][fn] = __builtin_amdgcn_mfma_f32_16x16x32_bf16(af[fm], bfr[fn], acc[fm][fn], 0, 0, 0);
    __syncthreads();
  }

  ushort* Cm = (bn < 4) ? Q2 : (bn < 8) ? K2 : V2;
  const int col  = (bn & 3) * 128 + wc * 64 + (lane & 15);
  const int row0 = bm * 128 + wr * 64 + (lane >> 4) * 4;
  #pragma unroll
  for (int fm = 0; fm < 4; ++fm)
    #pragma unroll
    for (int fn = 0; fn < 4; ++fn)
      #pragma unroll
      for (int r = 0; r < 4; ++r)
        Cm[(size_t)(row0 + fm * 16 + r) * 512 + col + fn * 16] = f2h(acc[fm][fn][r]);
}

// ---------------- knn: 8 queries/block, packed scan, low-LDS overlay -----
// s_dval (phase D) overlays s_tmax (dead after phase B) -> 12.4 KB LDS.
__global__ __launch_bounds__(256) void knn_kernel(
    const float4* __restrict__ gpk,
    const double* __restrict__ Gx, const double* __restrict__ Gy,
    const double* __restrict__ Gz, const double* __restrict__ Gsq,
    int* __restrict__ knn) {
  const int tid   = threadIdx.x;
  const int w     = tid >> 6;
  const int lane  = tid & 63;
  const int qbase = blockIdx.x * QPB;

  __shared__ unsigned long long ovl[QPB * 128];   // 8 KB: tmax (A/B) | dval (D)
  __shared__ int   s_cand[QPB][CAP];              // 4 KB
  __shared__ int   s_cnt[QPB];
  __shared__ float s_T[QPB];
  float (*s_tmax)[256] = (float(*)[256])ovl;
  double(*s_dval)[CAP] = (double(*)[CAP])ovl;

  float q2x[QPB], q2y[QPB], q2z[QPB];
  v2f tm2[QPB];
  #pragma unroll
  for (int s = 0; s < QPB; ++s) {
    float4 qv = gpk[qbase + s];
    q2x[s] = 2.f * qv.x; q2y[s] = 2.f * qv.y; q2z[s] = 2.f * qv.z;
    tm2[s] = splat2(-1e30f);
  }
  if (tid < QPB) s_cnt[tid] = 0;

  // Phase A: packed branchless max scan with register prefetch
  {
    float4 c0 = gpk[tid];
    float4 c1 = gpk[tid + 256];
    for (int i = 0; i < 16; ++i) {
      int nx = ((i + 1) & 15) * 512;
      float4 n0 = gpk[tid + nx];
      float4 n1 = gpk[tid + nx + 256];
      v2f cx, cy, cz, cw;
      cx.x = c0.x; cx.y = c1.x;
      cy.x = c0.y; cy.y = c1.y;
      cz.x = c0.z; cz.y = c1.z;
      cw.x = c0.w; cw.y = c1.w;
      #pragma unroll
      for (int s = 0; s < QPB; ++s) {
        v2f v = fma2(splat2(q2x[s]), cx,
                 fma2(splat2(q2y[s]), cy,
                  fma2(splat2(q2z[s]), cz, cw)));
        tm2[s] = max2(tm2[s], v);
      }
      c0 = n0; c1 = n1;
    }
  }
  #pragma unroll
  for (int s = 0; s < QPB; ++s) s_tmax[s][tid] = fmaxf(tm2[s].x, tm2[s].y);
  __syncthreads();

  // Phase B: wave w -> queries 2w, 2w+1; exact 16th-of-64 via radix select
  #pragma unroll
  for (int qq = 0; qq < 2; ++qq) {
    int q = w * 2 + qq;
    float v = fmaxf(fmaxf(s_tmax[q][lane], s_tmax[q][lane + 64]),
                    fmaxf(s_tmax[q][lane + 128], s_tmax[q][lane + 192]));
    unsigned b = __float_as_uint(v);
    unsigned u = b ^ ((unsigned)((int)b >> 31) | 0x80000000u);
    unsigned thr = 0;
    for (int bit = 31; bit >= 0; --bit) {
      unsigned cand = thr | (1u << bit);
      unsigned long long m = __ballot(u >= cand);
      if (__popcll(m) >= KN) thr = cand;
    }
    unsigned tb = (thr & 0x80000000u) ? (thr ^ 0x80000000u) : ~thr;
    if (lane == 0) s_T[q] = __uint_as_float(tb);
  }
  __syncthreads();

  // Phase C: packed rescan (identical FMA chain), collect candidates >= T
  float Ts[QPB];
  #pragma unroll
  for (int s = 0; s < QPB; ++s) Ts[s] = s_T[s];
  {
    float4 c0 = gpk[tid];
    float4 c1 = gpk[tid + 256];
    for (int i = 0; i < 16; ++i) {
      int nx = ((i + 1) & 15) * 512;
      float4 n0 = gpk[tid + nx];
      float4 n1 = gpk[tid + nx + 256];
      int j0 = tid + i * 512, j1 = j0 + 256;
      v2f cx, cy, cz, cw;
      cx.x = c0.x; cx.y = c1.x;
      cy.x = c0.y; cy.y = c1.y;
      cz.x = c0.z; cz.y = c1.z;
      cw.x = c0.w; cw.y = c1.w;
      #pragma unroll
      for (int s = 0; s < QPB; ++s) {
        v2f v = fma2(splat2(q2x[s]), cx,
                 fma2(splat2(q2y[s]), cy,
                  fma2(splat2(q2z[s]), cz, cw)));
        if (v.x >= Ts[s]) { int p = atomicAdd(&s_cnt[s], 1); if (p < CAP) s_cand[s][p] = j0; }
        if (v.y >= Ts[s]) { int p = atomicAdd(&s_cnt[s], 1); if (p < CAP) s_cand[s][p] = j1; }
      }
      c0 = n0; c1 = n1;
    }
  }
  __syncthreads();

  // Phase D: exact f64 scores, rank-by-counting (dval overlays dead tmax)
  const int qA = w * 2, qB = qA + 1;
  const int cntA = min(s_cnt[qA], CAP);
  const int cntB = min(s_cnt[qB], CAP);
  int j0a = -1, j1a = -1, j0b = -1, j1b = -1;
  double v0a = 0, v1a = 0, v0b = 0, v1b = 0;
  {
    int gq = qbase + qA;
    double xi = Gx[gq], yi = Gy[gq], zi = Gz[gq], sqi = Gsq[gq];
    if (lane < cntA) {
      j0a = s_cand[qA][lane];
      v0a = 2.0 * (xi * Gx[j0a] + yi * Gy[j0a] + zi * Gz[j0a]) - sqi - Gsq[j0a];
      s_dval[qA][lane] = v0a;
    }
    if (lane + 64 < cntA) {
      j1a = s_cand[qA][lane + 64];
      v1a = 2.0 * (xi * Gx[j1a] + yi * Gy[j1a] + zi * Gz[j1a]) - sqi - Gsq[j1a];
      s_dval[qA][lane + 64] = v1a;
    }
  }
  {
    int gq = qbase + qB;
    double xi = Gx[gq], yi = Gy[gq], zi = Gz[gq], sqi = Gsq[gq];
    if (lane < cntB) {
      j0b = s_cand[qB][lane];
      v0b = 2.0 * (xi * Gx[j0b] + yi * Gy[j0b] + zi * Gz[j0b]) - sqi - Gsq[j0b];
      s_dval[qB][lane] = v0b;
    }
    if (lane + 64 < cntB) {
      j1b = s_cand[qB][lane + 64];
      v1b = 2.0 * (xi * Gx[j1b] + yi * Gy[j1b] + zi * Gz[j1b]) - sqi - Gsq[j1b];
      s_dval[qB][lane + 64] = v1b;
    }
  }
  __syncthreads();
  {
    int r0 = 0, r1 = 0;
    for (int m = 0; m < cntA; ++m) {
      double dv = s_dval[qA][m]; int di = s_cand[qA][m];
      r0 += (dv > v0a) || (dv == v0a && di < j0a);
      r1 += (dv > v1a) || (dv == v1a && di < j1a);
    }
    int gq = qbase + qA;
    if (j0a >= 0 && r0 < KN) knn[gq * KN + r0] = j0a;
    if (j1a >= 0 && r1 < KN) knn[gq * KN + r1] = j1a;
  }
  {
    int r0 = 0, r1 = 0;
    for (int m = 0; m < cntB; ++m) {
      double dv = s_dval[qB][m]; int di = s_cand[qB][m];
      r0 += (dv > v0b) || (dv == v0b && di < j0b);
      r1 += (dv > v1b) || (dv == v1b && di < j1b);
    }
    int gq = qbase + qB;
    if (j0b >= 0 && r0 < KN) knn[gq * KN + r0] = j0b;
    if (j1b >= 0 && r1 < KN) knn[gq * KN + r1] = j1b;
  }
}

// ---------------- attend: per dst node, 16 neighbors, f16 Q/K/V ----------
__global__ __launch_bounds__(256) void attend_kernel(
    const ushort* __restrict__ Q2, const ushort* __restrict__ K2, const ushort* __restrict__ V2,
    const float4* __restrict__ gpk,
    const int* __restrict__ knn, float* __restrict__ out) {
  const int i    = blockIdx.x;
  const int tid  = threadIdx.x;
  const int wv   = tid >> 6;
  const int lane = tid & 63;

  __shared__ int   s_idx[KN];
  __shared__ float s_sc[KN];
  __shared__ float s_w[KN];
  __shared__ float s_se[KN];

  if (tid < KN) s_idx[tid] = knn[i * KN + tid];
  __syncthreads();

  uint4 qa = *(const uint4*)&Q2[(size_t)i * 512 + lane * 8];

  float partial[4];
  #pragma unroll
  for (int s = 0; s < 4; ++s) {
    int src = s_idx[wv * 4 + s];
    uint4 ka = *(const uint4*)&K2[(size_t)src * 512 + lane * 8];
    float acc = dot2acc(qa.x, ka.x, 0.f);
    acc = dot2acc(qa.y, ka.y, acc);
    acc = dot2acc(qa.z, ka.z, acc);
    acc = dot2acc(qa.w, ka.w, acc);
    partial[s] = acc;
  }
  #pragma unroll
  for (int s = 0; s < 4; ++s)
    #pragma unroll
    for (int off = 32; off; off >>= 1) partial[s] += __shfl_down(partial[s], off);

  if (lane == 0) {
    #pragma unroll
    for (int s = 0; s < 4; ++s) s_sc[wv * 4 + s] = partial[s];
  }
  __syncthreads();

  // 16 threads compute the 16 edge weights in parallel (2 expf each)
  if (tid < KN) {
    int e = tid;
    int src = s_idx[e];
    float4 gi = gpk[i];
    float4 gs = gpk[src];
    float sc = s_sc[e] * (1.f / 22.627417f);
    sc = fminf(fmaxf(sc, -5.f), 5.f);
    float se = expf(sc);
    float dx = gi.x - gs.x, dy = gi.y - gs.y, dz = gi.z - gs.z;
    float dd = -sqrtf(fmaf(dx, dx, fmaf(dy, dy, fmaf(dz, dz, 1e-6f))));
    float dc = fminf(fmaxf(dd * (1.f / 22.627417f), -5.f), 5.f);
    float de = expf(dc);
    s_se[e] = se;
    s_w[e]  = se * de;
  }
  __syncthreads();

  float z = 0.f;
  #pragma unroll
  for (int e = 0; e < KN; ++e) z += s_se[e];

  const int d = tid * 2;
  float a0 = 0.f, a1 = 0.f;
  #pragma unroll
  for (int e = 0; e < KN; ++e) {
    unsigned vv = *(const unsigned*)&V2[(size_t)s_idx[e] * 512 + d];
    h2 vh = __builtin_bit_cast(h2, vv);
    a0 = fmaf(s_w[e], (float)vh.x, a0);
    a1 = fmaf(s_w[e], (float)vh.y, a1);
  }
  float inv = (z > 0.f) ? (1.f / z) : 1.f;
  float2 o = make_float2(a0 * inv, a1 * inv);
  *(float2*)&out[(size_t)i * 512 + d] = o;
}

extern "C" void kernel_launch(void* const* d_in, const int* in_sizes, int n_in,
                              void* d_out, int out_size, void* d_ws, size_t ws_size,
                              hipStream_t stream) {
  const float* h  = (const float*)d_in[0];
  const float* Wq = (const float*)d_in[1];
  const float* Wk = (const float*)d_in[2];
  const float* Wv = (const float*)d_in[3];
  const float* Wg = (const float*)d_in[4];
  float* out = (float*)d_out;

  char* ws = (char*)d_ws;
  ushort* A2  = (ushort*)(ws);                 // 8 MB
  ushort* B   = (ushort*)(ws + (8u << 20));    // 1.5 MB
  ushort* Q2  = (ushort*)(ws + (10u << 20));   // 8 MB (f16)
  ushort* K2  = (ushort*)(ws + (18u << 20));   // 8 MB (f16)
  ushort* V2  = (ushort*)(ws + (26u << 20));   // 8 MB (f16)
  float4* gpk = (float4*)(ws + (34u << 20));   // 128 KB
  double* Gx  = (double*)(ws + (34u << 20) + (1u << 17));
  double* Gy  = Gx + N_NODES;
  double* Gz  = Gy + N_NODES;
  double* Gsq = Gz + N_NODES;
  int*    knn = (int*)(Gsq + N_NODES);         // 512 KB

  hipLaunchKernelGGL(prep_split, dim3(2048 + 768), dim3(256), 0, stream,
                     h, Wg, Wq, Wk, Wv, A2, B, Gx, Gy, Gz, Gsq, gpk);
  hipLaunchKernelGGL(gemm_qkv, dim3(768), dim3(256), 0, stream,
                     A2, B, Q2, K2, V2);
  hipLaunchKernelGGL(knn_kernel, dim3(N_NODES / QPB), dim3(256), 0, stream,
                     gpk, Gx, Gy, Gz, Gsq, knn);
  hipLaunchKernelGGL(attend_kernel, dim3(N_NODES), dim3(256), 0, stream,
                     Q2, K2, V2, gpk, knn, out);
}